// Round 1
// baseline (1253.460 us; speedup 1.0000x reference)
//
#include <hip/hip_runtime.h>
#include <hip/hip_bf16.h>

#define ALPHA 1.702f
#define GLIMIT 7.0f

typedef __attribute__((ext_vector_type(4))) float f32x4;
typedef __attribute__((ext_vector_type(8))) __bf16 bf16x8;

typedef __attribute__((address_space(3))) unsigned int as3_uint;
typedef const __attribute__((address_space(1))) unsigned int as1_uint;

__device__ __forceinline__ void async_copy16(void* lds, const void* g) {
    __builtin_amdgcn_global_load_lds((as1_uint*)g, (as3_uint*)lds, 16, 0, 0);
}

__device__ __forceinline__ short f2bf(float f) {
    unsigned u = __float_as_uint(f);
    unsigned r = (u + 0x7fffu + ((u >> 16) & 1u)) >> 16;
    return (short)r;
}

// ---------- fp32 -> bf16 straight convert (x) ----------
__global__ void cvt_bf16_kernel(const float* __restrict__ src,
                                short* __restrict__ dst, int n4) {
    int i = blockIdx.x * blockDim.x + threadIdx.x;
    if (i < n4) {
        float4 v = reinterpret_cast<const float4*>(src)[i];
        short4 o;
        o.x = f2bf(v.x); o.y = f2bf(v.y); o.z = f2bf(v.z); o.w = f2bf(v.w);
        reinterpret_cast<short4*>(dst)[i] = o;
    }
}

// ---------- fp32 [z][R][C] -> bf16 [z][C][R] transpose-convert ----------
__global__ void transpose_cvt(const float* __restrict__ src,
                              short* __restrict__ dst, int R, int C) {
    __shared__ float t[64][65];
    const int z  = blockIdx.z;
    const int c0 = blockIdx.x * 64;
    const int r0 = blockIdx.y * 64;
    const float* s = src + (size_t)z * R * C;
    short* d = dst + (size_t)z * R * C;
    const int tid = threadIdx.x;
#pragma unroll
    for (int i = 0; i < 16; ++i) {
        int idx = i * 256 + tid;
        int r = idx >> 6, c = idx & 63;
        t[r][c] = s[(size_t)(r0 + r) * C + c0 + c];
    }
    __syncthreads();
#pragma unroll
    for (int i = 0; i < 16; ++i) {
        int idx = i * 256 + tid;
        int r = idx >> 6, c = idx & 63;
        d[(size_t)(c0 + r) * R + r0 + c] = f2bf(t[c][r]);
    }
}

// ---------- GEMM1: gate_up = x @ Wgu^T(e) + bias -> GEGLU -> act (bf16) ----------
// xb:  [4096][2048] bf16 (M x K)
// wgt: [8][4096][2048] bf16 (N x K, pre-transposed)
// bias:[8][4096] fp32
// act: [8][4096][2048] bf16
__global__ __launch_bounds__(256, 2) void gemm1_geglu(
    const short* __restrict__ xb, const short* __restrict__ wgt,
    const float* __restrict__ bias, short* __restrict__ act) {
    const int e  = blockIdx.z;
    const int m0 = blockIdx.y * 128;
    const int n0 = blockIdx.x * 128;
    const int tid  = threadIdx.x;
    const int lane = tid & 63;
    const int wid  = tid >> 6;
    const int wr = wid >> 1, wc = wid & 1;

    __shared__ __align__(16) short As[128 * 64];
    __shared__ __align__(16) short Bs[128 * 64];

    const short* Ag = xb + (size_t)m0 * 2048;
    const short* Bg = wgt + (size_t)e * 4096 * 2048 + (size_t)n0 * 2048;

    f32x4 acc[4][4];
#pragma unroll
    for (int m = 0; m < 4; ++m)
#pragma unroll
        for (int n = 0; n < 4; ++n) acc[m][n] = (f32x4){0.f, 0.f, 0.f, 0.f};

    for (int kt = 0; kt < 32; ++kt) {
#pragma unroll
        for (int i = 0; i < 4; ++i) {
            int c = i * 256 + tid;      // 0..1023 chunks of 8 bf16
            int r = c >> 3;             // 0..127
            int kk = (c & 7) * 8;
            async_copy16(As + c * 8, Ag + (size_t)r * 2048 + kt * 64 + kk);
            async_copy16(Bs + c * 8, Bg + (size_t)r * 2048 + kt * 64 + kk);
        }
        __syncthreads();
#pragma unroll
        for (int ks = 0; ks < 2; ++ks) {
            bf16x8 a[4], b[4];
#pragma unroll
            for (int m = 0; m < 4; ++m)
                a[m] = *(const bf16x8*)&As[(wr * 64 + m * 16 + (lane & 15)) * 64 + ks * 32 + (lane >> 4) * 8];
#pragma unroll
            for (int n = 0; n < 4; ++n)
                b[n] = *(const bf16x8*)&Bs[(wc * 64 + n * 16 + (lane & 15)) * 64 + ks * 32 + (lane >> 4) * 8];
#pragma unroll
            for (int m = 0; m < 4; ++m)
#pragma unroll
                for (int n = 0; n < 4; ++n)
                    acc[m][n] = __builtin_amdgcn_mfma_f32_16x16x32_bf16(a[m], b[n], acc[m][n], 0, 0, 0);
        }
        __syncthreads();
    }

    // epilogue: bias + GEGLU (even col = gate, odd col = up), write act bf16
    const float* bs = bias + (size_t)e * 4096;
    short* actb = act + (size_t)e * 4096 * 2048;
    const int col0 = n0 + wc * 64;
    const int row0 = m0 + wr * 64;
    const bool isgate = (lane & 1) == 0;
#pragma unroll
    for (int m = 0; m < 4; ++m) {
        int r0 = row0 + m * 16 + ((lane >> 4) << 2);
#pragma unroll
        for (int n = 0; n < 4; ++n) {
            int c = col0 + n * 16 + (lane & 15);
            float bv = bs[c];
            float v[4], o[4];
#pragma unroll
            for (int j = 0; j < 4; ++j) v[j] = acc[m][n][j] + bv;
#pragma unroll
            for (int j = 0; j < 4; ++j) o[j] = __shfl_xor(v[j], 1, 64);
            int dcol = c >> 1;
            int jbase = isgate ? 0 : 2;
#pragma unroll
            for (int jj = 0; jj < 2; ++jj) {
                int j = jbase + jj;
                float g = isgate ? v[j] : o[j];
                float u = isgate ? o[j] : v[j];
                g = fminf(g, GLIMIT);
                u = fmaxf(fminf(u, GLIMIT), -GLIMIT);
                float glu = g / (1.f + __expf(-ALPHA * g));
                float a = (u + 1.f) * glu;
                actb[(size_t)(r0 + j) * 2048 + dcol] = f2bf(a);
            }
        }
    }
}

// ---------- GEMM2: out = sum_e rw[t,e] * (act[e] @ Wd^T(e) + bd[e]) ----------
// act: [8][4096][2048] bf16 (M x K per e)
// wdt: [8][2048][2048] bf16 (N x K per e, pre-transposed)
// dbias: [8][2048] fp32, rw: [4096][8] fp32, out: [4096][2048] fp32
__global__ __launch_bounds__(256, 2) void gemm2_down(
    const short* __restrict__ act, const short* __restrict__ wdt,
    const float* __restrict__ dbias, const float* __restrict__ rw,
    float* __restrict__ out) {
    const int m0 = blockIdx.y * 128;
    const int n0 = blockIdx.x * 128;
    const int tid  = threadIdx.x;
    const int lane = tid & 63;
    const int wid  = tid >> 6;
    const int wr = wid >> 1, wc = wid & 1;

    __shared__ __align__(16) short As[128 * 64];
    __shared__ __align__(16) short Bs[128 * 64];
    __shared__ float rws[128 * 8];

#pragma unroll
    for (int i = 0; i < 4; ++i)
        rws[i * 256 + tid] = rw[(size_t)m0 * 8 + i * 256 + tid];

    float fin[4][4][4];
#pragma unroll
    for (int m = 0; m < 4; ++m)
#pragma unroll
        for (int n = 0; n < 4; ++n)
#pragma unroll
            for (int j = 0; j < 4; ++j) fin[m][n][j] = 0.f;

    for (int e = 0; e < 8; ++e) {
        const short* Ag = act + (size_t)e * 4096 * 2048 + (size_t)m0 * 2048;
        const short* Bg = wdt + (size_t)e * 2048 * 2048 + (size_t)n0 * 2048;

        f32x4 acc[4][4];
#pragma unroll
        for (int m = 0; m < 4; ++m)
#pragma unroll
            for (int n = 0; n < 4; ++n) acc[m][n] = (f32x4){0.f, 0.f, 0.f, 0.f};

        for (int kt = 0; kt < 32; ++kt) {
#pragma unroll
            for (int i = 0; i < 4; ++i) {
                int c = i * 256 + tid;
                int r = c >> 3;
                int kk = (c & 7) * 8;
                async_copy16(As + c * 8, Ag + (size_t)r * 2048 + kt * 64 + kk);
                async_copy16(Bs + c * 8, Bg + (size_t)r * 2048 + kt * 64 + kk);
            }
            __syncthreads();
#pragma unroll
            for (int ks = 0; ks < 2; ++ks) {
                bf16x8 a[4], b[4];
#pragma unroll
                for (int m = 0; m < 4; ++m)
                    a[m] = *(const bf16x8*)&As[(wr * 64 + m * 16 + (lane & 15)) * 64 + ks * 32 + (lane >> 4) * 8];
#pragma unroll
                for (int n = 0; n < 4; ++n)
                    b[n] = *(const bf16x8*)&Bs[(wc * 64 + n * 16 + (lane & 15)) * 64 + ks * 32 + (lane >> 4) * 8];
#pragma unroll
                for (int m = 0; m < 4; ++m)
#pragma unroll
                    for (int n = 0; n < 4; ++n)
                        acc[m][n] = __builtin_amdgcn_mfma_f32_16x16x32_bf16(a[m], b[n], acc[m][n], 0, 0, 0);
            }
            __syncthreads();
        }

        // fold this expert: fin += rw[t,e] * (acc + bd[e][col])
        const float* bde = dbias + (size_t)e * 2048;
#pragma unroll
        for (int n = 0; n < 4; ++n) {
            int c = n0 + wc * 64 + n * 16 + (lane & 15);
            float bdv = bde[c];
#pragma unroll
            for (int m = 0; m < 4; ++m) {
                int rl = wr * 64 + m * 16 + ((lane >> 4) << 2);
#pragma unroll
                for (int j = 0; j < 4; ++j) {
                    float w = rws[(rl + j) * 8 + e];
                    fin[m][n][j] += w * (acc[m][n][j] + bdv);
                }
            }
        }
    }

#pragma unroll
    for (int m = 0; m < 4; ++m) {
        int r0 = m0 + wr * 64 + m * 16 + ((lane >> 4) << 2);
#pragma unroll
        for (int n = 0; n < 4; ++n) {
            int c = n0 + wc * 64 + n * 16 + (lane & 15);
#pragma unroll
            for (int j = 0; j < 4; ++j)
                out[(size_t)(r0 + j) * 2048 + c] = fin[m][n][j];
        }
    }
}

extern "C" void kernel_launch(void* const* d_in, const int* in_sizes, int n_in,
                              void* d_out, int out_size, void* d_ws, size_t ws_size,
                              hipStream_t stream) {
    const float* x   = (const float*)d_in[0];  // [2,2048,2048]
    const float* wgu = (const float*)d_in[1];  // [8,2048,4096]
    const float* bgu = (const float*)d_in[2];  // [8,4096]
    const float* wd  = (const float*)d_in[3];  // [8,2048,2048]
    const float* bd  = (const float*)d_in[4];  // [8,2048]
    const float* rw  = (const float*)d_in[5];  // [4096,8]
    float* out = (float*)d_out;                // [4096,2048] fp32

    char* ws = (char*)d_ws;
    short* xb   = (short*)(ws);                                      // 16 MB
    short* wgut = (short*)(ws + 16777216);                           // 128 MB
    short* wdt  = (short*)(ws + 16777216 + 134217728);               // 64 MB
    short* actb = (short*)(ws + 16777216 + 134217728 + 67108864);    // 128 MB

    cvt_bf16_kernel<<<8192, 256, 0, stream>>>(x, xb, 2097152);
    transpose_cvt<<<dim3(64, 32, 8), 256, 0, stream>>>(wgu, wgut, 2048, 4096);
    transpose_cvt<<<dim3(32, 32, 8), 256, 0, stream>>>(wd, wdt, 2048, 2048);
    gemm1_geglu<<<dim3(32, 32, 8), 256, 0, stream>>>(xb, wgut, bgu, actb);
    gemm2_down<<<dim3(16, 32), 256, 0, stream>>>(actb, wdt, bd, rw, out);
}

// Round 2
// 976.854 us; speedup vs baseline: 1.2832x; 1.2832x over previous
//
#include <hip/hip_runtime.h>
#include <hip/hip_bf16.h>

#define ALPHA 1.702f
#define GLIMIT 7.0f

typedef __attribute__((ext_vector_type(4))) float f32x4;
typedef __attribute__((ext_vector_type(8))) __bf16 bf16x8;

typedef __attribute__((address_space(3))) unsigned int as3_uint;
typedef const __attribute__((address_space(1))) unsigned int as1_uint;

__device__ __forceinline__ void async_copy16(void* lds, const void* g) {
    __builtin_amdgcn_global_load_lds((as1_uint*)g, (as3_uint*)lds, 16, 0, 0);
}

__device__ __forceinline__ short f2bf(float f) {
    unsigned u = __float_as_uint(f);
    unsigned r = (u + 0x7fffu + ((u >> 16) & 1u)) >> 16;
    return (short)r;
}

// ---------- fp32 -> bf16 straight convert (x) ----------
__global__ void cvt_bf16_kernel(const float* __restrict__ src,
                                short* __restrict__ dst, int n4) {
    int i = blockIdx.x * blockDim.x + threadIdx.x;
    if (i < n4) {
        float4 v = reinterpret_cast<const float4*>(src)[i];
        short4 o;
        o.x = f2bf(v.x); o.y = f2bf(v.y); o.z = f2bf(v.z); o.w = f2bf(v.w);
        reinterpret_cast<short4*>(dst)[i] = o;
    }
}

// ---------- fp32 [z][R][C] -> bf16 [z][C][R] transpose-convert ----------
__global__ void transpose_cvt(const float* __restrict__ src,
                              short* __restrict__ dst, int R, int C) {
    __shared__ float t[64][65];
    const int z  = blockIdx.z;
    const int c0 = blockIdx.x * 64;
    const int r0 = blockIdx.y * 64;
    const float* s = src + (size_t)z * R * C;
    short* d = dst + (size_t)z * R * C;
    const int tid = threadIdx.x;
#pragma unroll
    for (int i = 0; i < 16; ++i) {
        int idx = i * 256 + tid;
        int r = idx >> 6, c = idx & 63;
        t[r][c] = s[(size_t)(r0 + r) * C + c0 + c];
    }
    __syncthreads();
#pragma unroll
    for (int i = 0; i < 16; ++i) {
        int idx = i * 256 + tid;
        int r = idx >> 6, c = idx & 63;
        d[(size_t)(c0 + r) * R + r0 + c] = f2bf(t[c][r]);
    }
}

// =================== 256x256 8-phase GEMM core ===================
// BM=BN=256, BK=64, 512 threads = 8 waves (2M x 4N), per-wave C = 128x64
// (rows split: wr*64 in each 128-half; cols split: wcol*32 in each 128-half).
// LDS: 2 buffers x 4 half-tiles (A0,A1,B0,B1), each 128x64 bf16 = 16 KiB.
// Swizzle: 16B-slot ^= (row&7) on both staged source and ds_read.

struct Gemm1Src {
    const short* A; const short* B;
    __device__ __forceinline__ const short* operator()(int t, int h) const {
        const short* base = (h & 2) ? B : A;
        return base + ((size_t)(h & 1) << 18) + (size_t)t * 64;
    }
};

struct Gemm2Src {
    const short* act; const short* wdt; size_t aoff, boff; int kh;
    __device__ __forceinline__ const short* operator()(int t, int h) const {
        int g = (kh << 7) + t;
        int e = g >> 5;
        size_t ko = (size_t)(g & 31) << 6;
        if (h & 2) return wdt + ((size_t)e << 22) + boff + ((size_t)(h & 1) << 18) + ko;
        return act + ((size_t)e << 23) + aoff + ((size_t)(h & 1) << 18) + ko;
    }
};

#define PH_BAR()  __builtin_amdgcn_s_barrier()
#define PH_LGKM() do { asm volatile("s_waitcnt lgkmcnt(0)" ::: "memory"); \
                       __builtin_amdgcn_sched_barrier(0); } while (0)

template <typename Src>
__device__ __forceinline__ void gemm_8phase(const Src& src, int NT, char* smem,
                                            f32x4 (&acc)[8][4]) {
    const int tid  = threadIdx.x;
    const int lane = tid & 63;
    const int wid  = tid >> 6;
    const int wr   = wid >> 2;      // 0..1
    const int wcol = wid & 3;       // 0..3
    const int lhi  = lane >> 4;     // 0..3
    const int llo  = lane & 15;

    auto stage = [&](int buf, int h, const short* g) {
        char* dst = smem + buf * 65536 + h * 16384;
        {
            int c = tid, r = c >> 3, s = (c & 7) ^ (r & 7);
            async_copy16(dst + c * 16, g + (size_t)r * 2048 + s * 8);
        }
        {
            int c = tid + 512, r = c >> 3, s = (c & 7) ^ (r & 7);
            async_copy16(dst + c * 16, g + (size_t)r * 2048 + s * 8);
        }
    };
    auto ldfrag = [&](int buf, int h, int row, int slot) {
        return *(const bf16x8*)(smem + buf * 65536 + h * 16384 + row * 128 +
                                ((slot ^ (row & 7)) << 4));
    };

    // prologue: tile0 {A0,B0,B1,A1} + tile1 {A0,B0,B1}; 3 half-tiles left in flight
    stage(0, 0, src(0, 0)); stage(0, 2, src(0, 2));
    stage(0, 3, src(0, 3)); stage(0, 1, src(0, 1));
    if (NT > 1) {
        stage(1, 0, src(1, 0)); stage(1, 2, src(1, 2)); stage(1, 3, src(1, 3));
        asm volatile("s_waitcnt vmcnt(6)" ::: "memory");
    } else {
        asm volatile("s_waitcnt vmcnt(0)" ::: "memory");
    }
    PH_BAR();

    bf16x8 a[4][2], b[4][2];
    for (int t = 0; t < NT; ++t) {
        const int cur = t & 1, nxt = cur ^ 1;
        // ---- P0: read A0+B0 (12 reads), issue A1(t+1), MFMA (mh0,nh0) ----
#pragma unroll
        for (int m = 0; m < 4; ++m) {
            int row = wr * 64 + m * 16 + llo;
            a[m][0] = ldfrag(cur, 0, row, lhi);
            a[m][1] = ldfrag(cur, 0, row, 4 + lhi);
        }
#pragma unroll
        for (int n = 0; n < 2; ++n) {
            int row = wcol * 32 + n * 16 + llo;
            b[n][0] = ldfrag(cur, 2, row, lhi);
            b[n][1] = ldfrag(cur, 2, row, 4 + lhi);
        }
        if (t + 1 < NT) stage(nxt, 1, src(t + 1, 1));
        PH_BAR(); PH_LGKM();
        __builtin_amdgcn_s_setprio(1);
#pragma unroll
        for (int m = 0; m < 4; ++m)
#pragma unroll
            for (int n = 0; n < 2; ++n)
#pragma unroll
                for (int ks = 0; ks < 2; ++ks)
                    acc[m][n] = __builtin_amdgcn_mfma_f32_16x16x32_bf16(
                        a[m][ks], b[n][ks], acc[m][n], 0, 0, 0);
        __builtin_amdgcn_s_setprio(0);
        PH_BAR();
        // ---- P1: read B1 (4 reads), issue A0(t+2), MFMA (mh0,nh1) ----
#pragma unroll
        for (int n = 0; n < 2; ++n) {
            int row = wcol * 32 + n * 16 + llo;
            b[2 + n][0] = ldfrag(cur, 3, row, lhi);
            b[2 + n][1] = ldfrag(cur, 3, row, 4 + lhi);
        }
        if (t + 2 < NT) stage(cur, 0, src(t + 2, 0));
        PH_BAR(); PH_LGKM();
        __builtin_amdgcn_s_setprio(1);
#pragma unroll
        for (int m = 0; m < 4; ++m)
#pragma unroll
            for (int n = 2; n < 4; ++n)
#pragma unroll
                for (int ks = 0; ks < 2; ++ks)
                    acc[m][n] = __builtin_amdgcn_mfma_f32_16x16x32_bf16(
                        a[m][ks], b[n][ks], acc[m][n], 0, 0, 0);
        __builtin_amdgcn_s_setprio(0);
        PH_BAR();
        // ---- P2: read A1 (8 reads, reuse a regs), issue B0(t+2), MFMA (mh1,nh0) ----
#pragma unroll
        for (int m = 0; m < 4; ++m) {
            int row = wr * 64 + m * 16 + llo;
            a[m][0] = ldfrag(cur, 1, row, lhi);
            a[m][1] = ldfrag(cur, 1, row, 4 + lhi);
        }
        if (t + 2 < NT) stage(cur, 2, src(t + 2, 2));
        PH_BAR(); PH_LGKM();
        __builtin_amdgcn_s_setprio(1);
#pragma unroll
        for (int m = 0; m < 4; ++m)
#pragma unroll
            for (int n = 0; n < 2; ++n)
#pragma unroll
                for (int ks = 0; ks < 2; ++ks)
                    acc[4 + m][n] = __builtin_amdgcn_mfma_f32_16x16x32_bf16(
                        a[m][ks], b[n][ks], acc[4 + m][n], 0, 0, 0);
        __builtin_amdgcn_s_setprio(0);
        PH_BAR();
        // ---- P3: issue B1(t+2), counted vmcnt(6), MFMA (mh1,nh1) ----
        if (t + 2 < NT) {
            stage(cur, 3, src(t + 2, 3));
            asm volatile("s_waitcnt vmcnt(6)" ::: "memory");
        } else {
            asm volatile("s_waitcnt vmcnt(0)" ::: "memory");
        }
        PH_BAR();
        __builtin_amdgcn_s_setprio(1);
#pragma unroll
        for (int m = 0; m < 4; ++m)
#pragma unroll
            for (int n = 2; n < 4; ++n)
#pragma unroll
                for (int ks = 0; ks < 2; ++ks)
                    acc[4 + m][n] = __builtin_amdgcn_mfma_f32_16x16x32_bf16(
                        a[m][ks], b[n][ks], acc[4 + m][n], 0, 0, 0);
        __builtin_amdgcn_s_setprio(0);
        PH_BAR();
    }
}

// ---------- GEMM1: gate_up = x @ Wgu^T(e) + bias -> GEGLU -> *rw -> act ----------
__global__ __launch_bounds__(512, 2) void gemm1_8ph(
    const short* __restrict__ xb, const short* __restrict__ wgut,
    const float* __restrict__ bias, const float* __restrict__ rwp,
    short* __restrict__ act) {
    __shared__ __align__(16) char smem[131072];
    const int e = blockIdx.z;
    int flat = blockIdx.x + (blockIdx.y << 4);        // 0..255, 256%8==0
    int swz = (flat & 7) * 32 + (flat >> 3);
    const int n0 = (swz & 15) * 256;
    const int m0 = (swz >> 4) * 256;
    const int tid  = threadIdx.x;
    const int lane = tid & 63;
    const int wid  = tid >> 6;
    const int wr = wid >> 2, wcol = wid & 3;

    f32x4 acc[8][4];
#pragma unroll
    for (int m = 0; m < 8; ++m)
#pragma unroll
        for (int n = 0; n < 4; ++n) acc[m][n] = (f32x4){0.f, 0.f, 0.f, 0.f};

    Gemm1Src src{ xb + (size_t)m0 * 2048,
                  wgut + ((size_t)e << 23) + (size_t)n0 * 2048 };
    gemm_8phase(src, 32, smem, acc);

    // epilogue: stage rw rows, bias + GEGLU + rw-scale, write act bf16
    __syncthreads();
    float* rws = (float*)smem;
    if (tid < 256) rws[tid] = rwp[(size_t)(m0 + tid) * 8 + e];
    __syncthreads();

    const float* bias_e = bias + (size_t)e * 4096;
    short* acte = act + ((size_t)e << 23);
    const int par = lane & 1;
    float bvn[4];
#pragma unroll
    for (int n = 0; n < 4; ++n) {
        int coln = n0 + (n >> 1) * 128 + wcol * 32 + (n & 1) * 16 + (lane & 15);
        bvn[n] = bias_e[coln];
    }
#pragma unroll
    for (int m = 0; m < 8; ++m) {
        int rowb = (m >> 2) * 128 + wr * 64 + (m & 3) * 16 + ((lane >> 4) << 2);
#pragma unroll
        for (int n = 0; n < 4; ++n) {
            int coln = n0 + (n >> 1) * 128 + wcol * 32 + (n & 1) * 16 + (lane & 15);
            float v[4], o[4];
#pragma unroll
            for (int j = 0; j < 4; ++j) v[j] = acc[m][n][j] + bvn[n];
#pragma unroll
            for (int j = 0; j < 4; ++j) o[j] = __shfl_xor(v[j], 1);
            int dcol = coln >> 1;
#pragma unroll
            for (int jj = 0; jj < 2; ++jj) {
                int j = (par << 1) + jj;
                float g = par ? o[j] : v[j];
                float u = par ? v[j] : o[j];
                g = fminf(g, GLIMIT);
                u = fmaxf(fminf(u, GLIMIT), -GLIMIT);
                float glu = g / (1.f + __expf(-ALPHA * g));
                int row = rowb + j;
                float aa = (u + 1.f) * glu * rws[row];
                acte[(size_t)(m0 + row) * 2048 + dcol] = f2bf(aa);
            }
        }
    }
}

// ---------- GEMM2: split-K over experts; kh=0 -> out, kh=1 -> partial ----------
__global__ __launch_bounds__(512, 2) void gemm2_8ph(
    const short* __restrict__ act, const short* __restrict__ wdt,
    float* __restrict__ out, float* __restrict__ part) {
    __shared__ __align__(16) char smem[131072];
    const int kh = blockIdx.z;
    int flat = blockIdx.x + (blockIdx.y << 3);        // 0..127, 128%8==0
    int swz = (flat & 7) * 16 + (flat >> 3);
    const int n0 = (swz & 7) * 256;
    const int m0 = (swz >> 3) * 256;
    const int tid  = threadIdx.x;
    const int lane = tid & 63;
    const int wid  = tid >> 6;
    const int wr = wid >> 2, wcol = wid & 3;

    f32x4 acc[8][4];
#pragma unroll
    for (int m = 0; m < 8; ++m)
#pragma unroll
        for (int n = 0; n < 4; ++n) acc[m][n] = (f32x4){0.f, 0.f, 0.f, 0.f};

    Gemm2Src src{ act, wdt, (size_t)m0 * 2048, (size_t)n0 * 2048, kh };
    gemm_8phase(src, 128, smem, acc);

    float* dst = (kh == 0) ? out : part;
#pragma unroll
    for (int m = 0; m < 8; ++m) {
        int row = m0 + (m >> 2) * 128 + wr * 64 + (m & 3) * 16 + ((lane >> 4) << 2);
#pragma unroll
        for (int n = 0; n < 4; ++n) {
            int col = n0 + (n >> 1) * 128 + wcol * 32 + (n & 1) * 16 + (lane & 15);
#pragma unroll
            for (int j = 0; j < 4; ++j)
                dst[(size_t)(row + j) * 2048 + col] = acc[m][n][j];
        }
    }
}

// ---------- reduce: out += partial + sum_e rw[t,e]*bd[e,h] ----------
__global__ __launch_bounds__(256) void reduce_bias(
    const float* __restrict__ p1, const float* __restrict__ rw,
    const float* __restrict__ bd, float* __restrict__ out) {
    const int t = blockIdx.x;
    const int tid = threadIdx.x;
    float rwv[8];
#pragma unroll
    for (int e = 0; e < 8; ++e) rwv[e] = rw[(size_t)t * 8 + e];
    size_t base = (size_t)t * 2048;
#pragma unroll
    for (int i = 0; i < 2; ++i) {
        int h = (tid + i * 256) * 4;
        float4 o = *(const float4*)(out + base + h);
        float4 p = *(const float4*)(p1 + base + h);
        o.x += p.x; o.y += p.y; o.z += p.z; o.w += p.w;
#pragma unroll
        for (int e = 0; e < 8; ++e) {
            float4 bb = *(const float4*)(bd + e * 2048 + h);
            o.x += rwv[e] * bb.x; o.y += rwv[e] * bb.y;
            o.z += rwv[e] * bb.z; o.w += rwv[e] * bb.w;
        }
        *(float4*)(out + base + h) = o;
    }
}

extern "C" void kernel_launch(void* const* d_in, const int* in_sizes, int n_in,
                              void* d_out, int out_size, void* d_ws, size_t ws_size,
                              hipStream_t stream) {
    const float* x   = (const float*)d_in[0];  // [2,2048,2048]
    const float* wgu = (const float*)d_in[1];  // [8,2048,4096]
    const float* bgu = (const float*)d_in[2];  // [8,4096]
    const float* wd  = (const float*)d_in[3];  // [8,2048,2048]
    const float* bd  = (const float*)d_in[4];  // [8,2048]
    const float* rw  = (const float*)d_in[5];  // [4096,8]
    float* out = (float*)d_out;                // [4096,2048] fp32

    char* ws = (char*)d_ws;
    short* xb   = (short*)(ws);                         // 16 MB
    short* wgut = (short*)(ws + 16777216);              // 128 MB (dead after gemm1)
    float* p1   = (float*)(ws + 16777216);              // 32 MB, aliases wgut
    short* wdt  = (short*)(ws + 150994944);             // 64 MB
    short* actb = (short*)(ws + 218103808);             // 128 MB

    cvt_bf16_kernel<<<8192, 256, 0, stream>>>(x, xb, 2097152);
    transpose_cvt<<<dim3(64, 32, 8), 256, 0, stream>>>(wgu, wgut, 2048, 4096);
    transpose_cvt<<<dim3(32, 32, 8), 256, 0, stream>>>(wd, wdt, 2048, 2048);
    gemm1_8ph<<<dim3(16, 16, 8), 512, 0, stream>>>(xb, wgut, bgu, rw, actb);
    gemm2_8ph<<<dim3(8, 16, 2), 512, 0, stream>>>(actb, wdt, out, p1);
    reduce_bias<<<4096, 256, 0, stream>>>(p1, rw, bd, out);
}

// Round 3
// 964.062 us; speedup vs baseline: 1.3002x; 1.0133x over previous
//
#include <hip/hip_runtime.h>
#include <hip/hip_bf16.h>

#define ALPHA 1.702f
#define GLIMIT 7.0f

typedef __attribute__((ext_vector_type(4))) float f32x4;
typedef __attribute__((ext_vector_type(8))) __bf16 bf16x8;
typedef __attribute__((ext_vector_type(8))) short short8;

typedef __attribute__((address_space(3))) unsigned int as3_uint;
typedef const __attribute__((address_space(1))) unsigned int as1_uint;

__device__ __forceinline__ void async_copy16(void* lds, const void* g) {
    __builtin_amdgcn_global_load_lds((as1_uint*)g, (as3_uint*)lds, 16, 0, 0);
}

__device__ __forceinline__ short f2bf(float f) {
    unsigned u = __float_as_uint(f);
    unsigned r = (u + 0x7fffu + ((u >> 16) & 1u)) >> 16;
    return (short)r;
}

// ---------- fp32 -> bf16 straight convert (x) ----------
__global__ void cvt_bf16_kernel(const float* __restrict__ src,
                                short* __restrict__ dst, int n4) {
    int i = blockIdx.x * blockDim.x + threadIdx.x;
    if (i < n4) {
        float4 v = reinterpret_cast<const float4*>(src)[i];
        short4 o;
        o.x = f2bf(v.x); o.y = f2bf(v.y); o.z = f2bf(v.z); o.w = f2bf(v.w);
        reinterpret_cast<short4*>(dst)[i] = o;
    }
}

// ---------- fp32 [z][R][C] -> bf16 [z][C][R] transpose-convert ----------
__global__ void transpose_cvt(const float* __restrict__ src,
                              short* __restrict__ dst, int R, int C) {
    __shared__ float t[64][65];
    const int z  = blockIdx.z;
    const int c0 = blockIdx.x * 64;
    const int r0 = blockIdx.y * 64;
    const float* s = src + (size_t)z * R * C;
    short* d = dst + (size_t)z * R * C;
    const int tid = threadIdx.x;
#pragma unroll
    for (int i = 0; i < 16; ++i) {
        int idx = i * 256 + tid;
        int r = idx >> 6, c = idx & 63;
        t[r][c] = s[(size_t)(r0 + r) * C + c0 + c];
    }
    __syncthreads();
#pragma unroll
    for (int i = 0; i < 16; ++i) {
        int idx = i * 256 + tid;
        int r = idx >> 6, c = idx & 63;
        d[(size_t)(c0 + r) * R + r0 + c] = f2bf(t[c][r]);
    }
}

// =================== 256x256 8-phase GEMM core ===================
// BM=BN=256, BK=64, 512 threads = 8 waves (2M x 4N), per-wave C = 128x64.
// LDS: 2 buffers x 4 half-tiles (A0,A1,B0,B1), each 128x64 bf16 = 16 KiB.
// Swizzle: 16B-slot ^= (row&7) on both staged source and ds_read.
// vmcnt schedule: P1 waits vmcnt(10) (forces A1(t), 5-phase cover);
// P3 waits vmcnt(8) (forces A0/B0/B1(t+1), 4-6 phase cover). 7 stages
// (14 loads) max in flight across 7 distinct LDS slots.

struct Gemm1Src {
    const short* A; const short* B;
    __device__ __forceinline__ const short* operator()(int t, int h) const {
        const short* base = (h & 2) ? B : A;
        return base + ((size_t)(h & 1) << 18) + (size_t)t * 64;
    }
};

struct Gemm2Src {
    const short* act; const short* wdt; size_t aoff, boff; int kh;
    __device__ __forceinline__ const short* operator()(int t, int h) const {
        int g = (kh << 7) + t;
        int e = g >> 5;
        size_t ko = (size_t)(g & 31) << 6;
        if (h & 2) return wdt + ((size_t)e << 22) + boff + ((size_t)(h & 1) << 18) + ko;
        return act + ((size_t)e << 23) + aoff + ((size_t)(h & 1) << 18) + ko;
    }
};

#define PH_BAR()  __builtin_amdgcn_s_barrier()
#define PH_LGKM() do { asm volatile("s_waitcnt lgkmcnt(0)" ::: "memory"); \
                       __builtin_amdgcn_sched_barrier(0); } while (0)
#define VMW(n)    asm volatile("s_waitcnt vmcnt(" #n ")" ::: "memory")

template <typename Src>
__device__ __forceinline__ void gemm_8phase(const Src& src, int NT, char* smem,
                                            f32x4 (&acc)[8][4]) {
    const int tid  = threadIdx.x;
    const int lane = tid & 63;
    const int wid  = tid >> 6;
    const int wr   = wid >> 2;      // 0..1
    const int wcol = wid & 3;       // 0..3
    const int lhi  = lane >> 4;     // 0..3
    const int llo  = lane & 15;

    auto stage = [&](int buf, int h, const short* g) {
        char* dst = smem + buf * 65536 + h * 16384;
        {
            int c = tid, r = c >> 3, s = (c & 7) ^ (r & 7);
            async_copy16(dst + c * 16, g + (size_t)r * 2048 + s * 8);
        }
        {
            int c = tid + 512, r = c >> 3, s = (c & 7) ^ (r & 7);
            async_copy16(dst + c * 16, g + (size_t)r * 2048 + s * 8);
        }
    };
    auto ldfrag = [&](int buf, int h, int row, int slot) {
        return *(const bf16x8*)(smem + buf * 65536 + h * 16384 + row * 128 +
                                ((slot ^ (row & 7)) << 4));
    };

    // prologue: tile0 {A0,B0,B1,A1} + tile1 {A0,B0,B1}; keep 4 stages in flight
    stage(0, 0, src(0, 0)); stage(0, 2, src(0, 2));
    stage(0, 3, src(0, 3)); stage(0, 1, src(0, 1));
    stage(1, 0, src(1, 0)); stage(1, 2, src(1, 2)); stage(1, 3, src(1, 3));
    VMW(8);
    PH_BAR();

    bf16x8 a[4][2], b[4][2];
    // peel: B0(0) -> b[0..1]
#pragma unroll
    for (int n = 0; n < 2; ++n) {
        int row = wcol * 32 + n * 16 + llo;
        b[n][0] = ldfrag(0, 2, row, lhi);
        b[n][1] = ldfrag(0, 2, row, 4 + lhi);
    }

    for (int t = 0; t < NT; ++t) {
        const int cur = t & 1, nxt = cur ^ 1;
        // ---- P0: read A0(t) (8); stage A1(t+1); MFMA (mh0,nh0) ----
#pragma unroll
        for (int m = 0; m < 4; ++m) {
            int row = wr * 64 + m * 16 + llo;
            a[m][0] = ldfrag(cur, 0, row, lhi);
            a[m][1] = ldfrag(cur, 0, row, 4 + lhi);
        }
        if (t + 1 < NT) stage(nxt, 1, src(t + 1, 1));
        PH_BAR(); PH_LGKM();
        __builtin_amdgcn_s_setprio(1);
#pragma unroll
        for (int m = 0; m < 4; ++m)
#pragma unroll
            for (int n = 0; n < 2; ++n)
#pragma unroll
                for (int ks = 0; ks < 2; ++ks)
                    acc[m][n] = __builtin_amdgcn_mfma_f32_16x16x32_bf16(
                        a[m][ks], b[n][ks], acc[m][n], 0, 0, 0);
        __builtin_amdgcn_s_setprio(0);
        PH_BAR();
        // ---- P1: read B1(t) (4); stage A0(t+2); vmcnt(10); MFMA (mh0,nh1) ----
#pragma unroll
        for (int n = 0; n < 2; ++n) {
            int row = wcol * 32 + n * 16 + llo;
            b[2 + n][0] = ldfrag(cur, 3, row, lhi);
            b[2 + n][1] = ldfrag(cur, 3, row, 4 + lhi);
        }
        if (t + 2 < NT) { stage(cur, 0, src(t + 2, 0)); VMW(10); }
        else if (t + 1 < NT) { VMW(8); }
        else { VMW(0); }
        PH_BAR(); PH_LGKM();
        __builtin_amdgcn_s_setprio(1);
#pragma unroll
        for (int m = 0; m < 4; ++m)
#pragma unroll
            for (int n = 2; n < 4; ++n)
#pragma unroll
                for (int ks = 0; ks < 2; ++ks)
                    acc[m][n] = __builtin_amdgcn_mfma_f32_16x16x32_bf16(
                        a[m][ks], b[n][ks], acc[m][n], 0, 0, 0);
        __builtin_amdgcn_s_setprio(0);
        PH_BAR();
        // ---- P2: read A1(t) (8); stage B0(t+2); MFMA (mh1,nh0) ----
#pragma unroll
        for (int m = 0; m < 4; ++m) {
            int row = wr * 64 + m * 16 + llo;
            a[m][0] = ldfrag(cur, 1, row, lhi);
            a[m][1] = ldfrag(cur, 1, row, 4 + lhi);
        }
        if (t + 2 < NT) stage(cur, 2, src(t + 2, 2));
        PH_BAR(); PH_LGKM();
        __builtin_amdgcn_s_setprio(1);
#pragma unroll
        for (int m = 0; m < 4; ++m)
#pragma unroll
            for (int n = 0; n < 2; ++n)
#pragma unroll
                for (int ks = 0; ks < 2; ++ks)
                    acc[4 + m][n] = __builtin_amdgcn_mfma_f32_16x16x32_bf16(
                        a[m][ks], b[n][ks], acc[4 + m][n], 0, 0, 0);
        __builtin_amdgcn_s_setprio(0);
        PH_BAR();
        // ---- P3: stage B1(t+2); vmcnt(8); read B0(t+1) in-region; MFMA (mh1,nh1) ----
        if (t + 2 < NT) { stage(cur, 3, src(t + 2, 3)); VMW(8); }
        else if (t + 1 < NT) { VMW(2); }
        else { VMW(0); }
        PH_BAR(); PH_LGKM();
        __builtin_amdgcn_s_setprio(1);
        if (t + 1 < NT) {
#pragma unroll
            for (int n = 0; n < 2; ++n) {
                int row = wcol * 32 + n * 16 + llo;
                b[n][0] = ldfrag(nxt, 2, row, lhi);
                b[n][1] = ldfrag(nxt, 2, row, 4 + lhi);
            }
        }
#pragma unroll
        for (int m = 0; m < 4; ++m)
#pragma unroll
            for (int n = 2; n < 4; ++n)
#pragma unroll
                for (int ks = 0; ks < 2; ++ks)
                    acc[4 + m][n] = __builtin_amdgcn_mfma_f32_16x16x32_bf16(
                        a[m][ks], b[n][ks], acc[4 + m][n], 0, 0, 0);
        __builtin_amdgcn_s_setprio(0);
        PH_BAR();
    }
}

// ---------- GEMM1: gate_up = x @ Wgu^T(e) + bias -> GEGLU -> *rw -> act ----------
__global__ __launch_bounds__(512, 2) void gemm1_8ph(
    const short* __restrict__ xb, const short* __restrict__ wgut,
    const float* __restrict__ bias, const float* __restrict__ rwp,
    short* __restrict__ act) {
    __shared__ __align__(16) char smem[131072];
    const int e = blockIdx.z;
    int flat = blockIdx.x + (blockIdx.y << 4);        // 0..255, 256%8==0
    int swz = (flat & 7) * 32 + (flat >> 3);
    const int n0 = (swz & 15) * 256;
    const int m0 = (swz >> 4) * 256;
    const int tid  = threadIdx.x;
    const int lane = tid & 63;
    const int wid  = tid >> 6;
    const int wr = wid >> 2, wcol = wid & 3;
    const int lhi = lane >> 4, llo = lane & 15;

    f32x4 acc[8][4];
#pragma unroll
    for (int m = 0; m < 8; ++m)
#pragma unroll
        for (int n = 0; n < 4; ++n) acc[m][n] = (f32x4){0.f, 0.f, 0.f, 0.f};

    Gemm1Src src{ xb + (size_t)m0 * 2048,
                  wgut + ((size_t)e << 23) + (size_t)n0 * 2048 };
    gemm_8phase(src, 32, smem, acc);

    // ---- epilogue: rws stage, GEGLU -> LDS repack -> coalesced bf16 stores ----
    short* lact = (short*)smem;                    // [256][136] pitch (272 B)
    float* rws  = (float*)(smem + 69632);
    if (tid < 256) rws[tid] = rwp[(size_t)(m0 + tid) * 8 + e];
    __syncthreads();

    const float* bias_e = bias + (size_t)e * 4096;
    const int par = lane & 1;
#pragma unroll
    for (int n = 0; n < 4; ++n) {
        int clocal = (n >> 1) * 128 + wcol * 32 + (n & 1) * 16 + llo;
        float bv = bias_e[n0 + clocal];
        int dloc = clocal >> 1;
#pragma unroll
        for (int m = 0; m < 8; ++m) {
            int rowb = (m >> 2) * 128 + wr * 64 + (m & 3) * 16 + (lhi << 2);
            float v[4], o[4];
#pragma unroll
            for (int j = 0; j < 4; ++j) v[j] = acc[m][n][j] + bv;
#pragma unroll
            for (int j = 0; j < 4; ++j) o[j] = __shfl_xor(v[j], 1);
#pragma unroll
            for (int jj = 0; jj < 2; ++jj) {
                int j = (par << 1) + jj;
                float g = par ? o[j] : v[j];
                float u = par ? v[j] : o[j];
                g = fminf(g, GLIMIT);
                u = fmaxf(fminf(u, GLIMIT), -GLIMIT);
                float glu = g / (1.f + __expf(-ALPHA * g));
                int row = rowb + j;
                lact[row * 136 + dloc] = f2bf((u + 1.f) * glu * rws[row]);
            }
        }
    }
    __syncthreads();
    short* acte = act + ((size_t)e << 23) + (size_t)m0 * 2048 + (n0 >> 1);
#pragma unroll
    for (int it = 0; it < 8; ++it) {
        int idx = it * 512 + tid;
        int row = idx >> 4, c8 = (idx & 15) << 3;
        *(short8*)(acte + (size_t)row * 2048 + c8) =
            *(const short8*)(lact + row * 136 + c8);
    }
}

// ---------- GEMM2: split-K over experts; kh=0 -> out, kh=1 -> partial ----------
__global__ __launch_bounds__(512, 2) void gemm2_8ph(
    const short* __restrict__ act, const short* __restrict__ wdt,
    float* __restrict__ out, float* __restrict__ part) {
    __shared__ __align__(16) char smem[131072];
    const int kh = blockIdx.z;
    int flat = blockIdx.x + (blockIdx.y << 3);        // 0..127, 128%8==0
    int swz = (flat & 7) * 16 + (flat >> 3);
    const int n0 = (swz & 7) * 256;
    const int m0 = (swz >> 3) * 256;
    const int tid  = threadIdx.x;
    const int lane = tid & 63;
    const int wid  = tid >> 6;
    const int wr = wid >> 2, wcol = wid & 3;

    f32x4 acc[8][4];
#pragma unroll
    for (int m = 0; m < 8; ++m)
#pragma unroll
        for (int n = 0; n < 4; ++n) acc[m][n] = (f32x4){0.f, 0.f, 0.f, 0.f};

    Gemm2Src src{ act, wdt, (size_t)m0 * 2048, (size_t)n0 * 2048, kh };
    gemm_8phase(src, 128, smem, acc);

    float* dst = (kh == 0) ? out : part;
#pragma unroll
    for (int m = 0; m < 8; ++m) {
        int row = m0 + (m >> 2) * 128 + wr * 64 + (m & 3) * 16 + ((lane >> 4) << 2);
#pragma unroll
        for (int n = 0; n < 4; ++n) {
            int col = n0 + (n >> 1) * 128 + wcol * 32 + (n & 1) * 16 + (lane & 15);
#pragma unroll
            for (int j = 0; j < 4; ++j)
                dst[(size_t)(row + j) * 2048 + col] = acc[m][n][j];
        }
    }
}

// ---------- reduce: out += partial + sum_e rw[t,e]*bd[e,h] ----------
__global__ __launch_bounds__(256) void reduce_bias(
    const float* __restrict__ p1, const float* __restrict__ rw,
    const float* __restrict__ bd, float* __restrict__ out) {
    const int t = blockIdx.x;
    const int tid = threadIdx.x;
    float rwv[8];
#pragma unroll
    for (int e = 0; e < 8; ++e) rwv[e] = rw[(size_t)t * 8 + e];
    size_t base = (size_t)t * 2048;
#pragma unroll
    for (int i = 0; i < 2; ++i) {
        int h = (tid + i * 256) * 4;
        float4 o = *(const float4*)(out + base + h);
        float4 p = *(const float4*)(p1 + base + h);
        o.x += p.x; o.y += p.y; o.z += p.z; o.w += p.w;
#pragma unroll
        for (int e = 0; e < 8; ++e) {
            float4 bb = *(const float4*)(bd + e * 2048 + h);
            o.x += rwv[e] * bb.x; o.y += rwv[e] * bb.y;
            o.z += rwv[e] * bb.z; o.w += rwv[e] * bb.w;
        }
        *(float4*)(out + base + h) = o;
    }
}

extern "C" void kernel_launch(void* const* d_in, const int* in_sizes, int n_in,
                              void* d_out, int out_size, void* d_ws, size_t ws_size,
                              hipStream_t stream) {
    const float* x   = (const float*)d_in[0];  // [2,2048,2048]
    const float* wgu = (const float*)d_in[1];  // [8,2048,4096]
    const float* bgu = (const float*)d_in[2];  // [8,4096]
    const float* wd  = (const float*)d_in[3];  // [8,2048,2048]
    const float* bd  = (const float*)d_in[4];  // [8,2048]
    const float* rw  = (const float*)d_in[5];  // [4096,8]
    float* out = (float*)d_out;                // [4096,2048] fp32

    char* ws = (char*)d_ws;
    short* xb   = (short*)(ws);                         // 16 MB
    short* wgut = (short*)(ws + 16777216);              // 128 MB (dead after gemm1)
    float* p1   = (float*)(ws + 16777216);              // 32 MB, aliases wgut
    short* wdt  = (short*)(ws + 150994944);             // 64 MB
    short* actb = (short*)(ws + 218103808);             // 128 MB

    cvt_bf16_kernel<<<8192, 256, 0, stream>>>(x, xb, 2097152);
    transpose_cvt<<<dim3(64, 32, 8), 256, 0, stream>>>(wgu, wgut, 2048, 4096);
    transpose_cvt<<<dim3(32, 32, 8), 256, 0, stream>>>(wd, wdt, 2048, 2048);
    gemm1_8ph<<<dim3(16, 16, 8), 512, 0, stream>>>(xb, wgut, bgu, rw, actb);
    gemm2_8ph<<<dim3(8, 16, 2), 512, 0, stream>>>(actb, wdt, out, p1);
    reduce_bias<<<4096, 256, 0, stream>>>(p1, rw, bd, out);
}